// Round 1
// 325.841 us; speedup vs baseline: 1.1683x; 1.1683x over previous
//
#include <hip/hip_runtime.h>

// out = x + alpha * softmax(beta * x @ K^T) @ V
// B=4096, N=16384, D=1024, fp32 in/out.
// R3 changes vs R2:
//  - GEMM rewritten as 256x256-tile 8-phase schedule (8 waves, BK=64,
//    128 KiB LDS double-buffer, mfma_f32_16x16x32_f16):
//      * quadrant phases P1..P4 per K-tile: (A0,B0),(A0,B1),(A1,B0),(A1,B1)
//      * counted vmcnt: steady state issues A1(t+1)@P1, B1(t+1)@P2,
//        A0(t+2)@P3, B0(t+2)@P4; drains vmcnt(6) after P1, vmcnt(8) after P4.
//        Ledger verified: every half-tile drained before first ds_read; every
//        staging write targets a region whose last read finished >=1 barrier ago.
//      * K=1024 fixed -> 16 K-tiles; last two peeled with vmcnt(6,4)/vmcnt(0).
//      * LDS chunk-rotation swizzle slot=(chunk+row)&7 per 128B row ->
//        conflict-free ds_read_b128 (8 reads per 4-bank group). Applied by
//        pre-rotating the *global* source column per staging lane.
//      * s_setprio(1) around each 16-MFMA cluster (T5), XCD-aware block swizzle.
//  - softmax_gather unchanged.

typedef float    f32x4  __attribute__((ext_vector_type(4)));
typedef _Float16 f16x8  __attribute__((ext_vector_type(8)));
typedef _Float16 f16x4  __attribute__((ext_vector_type(4)));

#define LOG2E 1.44269504088896340736f
#define MAXSEL 1024
#define KK 1024   // K (= D) is fixed for this problem shape
#define NT 16     // K-tiles of 64

__device__ __forceinline__ void lds_load16(const void* g, void* l) {
    __builtin_amdgcn_global_load_lds(
        (__attribute__((address_space(1))) void*)(uintptr_t)g,
        (__attribute__((address_space(3))) void*)l,
        16, 0, 0);
}

template<int N> __device__ __forceinline__ void vwait() {
    if constexpr (N == 8)      asm volatile("s_waitcnt vmcnt(8)" ::: "memory");
    else if constexpr (N == 6) asm volatile("s_waitcnt vmcnt(6)" ::: "memory");
    else if constexpr (N == 4) asm volatile("s_waitcnt vmcnt(4)" ::: "memory");
    else if constexpr (N == 0) asm volatile("s_waitcnt vmcnt(0)" ::: "memory");
    // N == -1: no wait
}

__global__ void convert_f32_f16(const float* __restrict__ a, _Float16* __restrict__ o, long n4) {
    long i = (long)blockIdx.x * blockDim.x + threadIdx.x;
    if (i < n4) {
        f32x4 f = ((const f32x4*)a)[i];
        ((f16x4*)o)[i] = __builtin_convertvector(f, f16x4);
    }
}

// Stage one half-tile (128 rows x 64 halves) of a row-major [*, KK] f16 matrix
// into LDS. LDS side is lane-linear (global_load_lds requirement); the chunk
// rotation slot=(chunk+row)&7 is realized by rotating the GLOBAL source column.
// Two per-thread loads (rows r and r+64). One call = 2 vmcnt entries.
__device__ __forceinline__ void stage_half(const _Float16* __restrict__ g,
                                           int k0, _Float16* lds_half, int tid) {
    const int r = tid >> 3;                        // 0..63
    const int c = ((tid & 7) - (r & 7)) & 7;       // source chunk for slot tid&7
    const _Float16* s0 = g + (long)r * KK + k0 + c * 8;
    _Float16* d = lds_half + (tid >> 6) * 512;     // wave-uniform base; HW adds lane*16B
    lds_load16(s0, d);
    lds_load16(s0 + 64 * KK, d + 4096);
}

// One K-tile (BK=64) of the 8-phase schedule. Ac/Bc: current LDS buffer
// (A,B regions, 16384 halves each). An/Bn: other buffer. kt: K-tile index.
// acc[mh][mi][nh][nj] = f32x4 fragment.
template<bool IA1, bool IB1, bool IA0, bool IB0, int D2, int D1>
__device__ __forceinline__ void tile_body(
    _Float16* Ac, _Float16* Bc, _Float16* An, _Float16* Bn,
    const _Float16* __restrict__ Ag, const _Float16* __restrict__ Bg, int kt,
    const int (&aoff)[4][2], const int (&boff)[2][2],
    int tid, f32x4 (&acc)[2][4][2][2])
{
    f16x8 a[4][2];
    f16x8 b[2][2][2];

    // ---- P1: quadrant (mh=0, nh=0) ----
#pragma unroll
    for (int mi = 0; mi < 4; ++mi)
#pragma unroll
        for (int ks = 0; ks < 2; ++ks)
            a[mi][ks] = *(const f16x8*)&Ac[aoff[mi][ks]];
#pragma unroll
    for (int nj = 0; nj < 2; ++nj)
#pragma unroll
        for (int ks = 0; ks < 2; ++ks)
            b[0][nj][ks] = *(const f16x8*)&Bc[boff[nj][ks]];
    if (IA1) stage_half(Ag + 128L * KK, (kt + 1) * 64, An + 8192, tid);
    __builtin_amdgcn_s_barrier();
    asm volatile("s_waitcnt lgkmcnt(0)" ::: "memory");
    __builtin_amdgcn_sched_barrier(0);
    __builtin_amdgcn_s_setprio(1);
#pragma unroll
    for (int mi = 0; mi < 4; ++mi)
#pragma unroll
        for (int nj = 0; nj < 2; ++nj)
#pragma unroll
            for (int ks = 0; ks < 2; ++ks)
                acc[0][mi][0][nj] = __builtin_amdgcn_mfma_f32_16x16x32_f16(
                    a[mi][ks], b[0][nj][ks], acc[0][mi][0][nj], 0, 0, 0);
    __builtin_amdgcn_s_setprio(0);
    vwait<D2>();
    __builtin_amdgcn_s_barrier();

    // ---- P2: quadrant (0,1) ----
#pragma unroll
    for (int nj = 0; nj < 2; ++nj)
#pragma unroll
        for (int ks = 0; ks < 2; ++ks)
            b[1][nj][ks] = *(const f16x8*)&Bc[boff[nj][ks] + 8192];
    if (IB1) stage_half(Bg + 128L * KK, (kt + 1) * 64, Bn + 8192, tid);
    __builtin_amdgcn_s_barrier();
    asm volatile("s_waitcnt lgkmcnt(0)" ::: "memory");
    __builtin_amdgcn_sched_barrier(0);
    __builtin_amdgcn_s_setprio(1);
#pragma unroll
    for (int mi = 0; mi < 4; ++mi)
#pragma unroll
        for (int nj = 0; nj < 2; ++nj)
#pragma unroll
            for (int ks = 0; ks < 2; ++ks)
                acc[0][mi][1][nj] = __builtin_amdgcn_mfma_f32_16x16x32_f16(
                    a[mi][ks], b[1][nj][ks], acc[0][mi][1][nj], 0, 0, 0);
    __builtin_amdgcn_s_setprio(0);
    __builtin_amdgcn_s_barrier();

    // ---- P3: quadrant (1,0) ----
#pragma unroll
    for (int mi = 0; mi < 4; ++mi)
#pragma unroll
        for (int ks = 0; ks < 2; ++ks)
            a[mi][ks] = *(const f16x8*)&Ac[aoff[mi][ks] + 8192];
    if (IA0) stage_half(Ag, (kt + 2) * 64, Ac, tid);
    __builtin_amdgcn_s_barrier();
    asm volatile("s_waitcnt lgkmcnt(0)" ::: "memory");
    __builtin_amdgcn_sched_barrier(0);
    __builtin_amdgcn_s_setprio(1);
#pragma unroll
    for (int mi = 0; mi < 4; ++mi)
#pragma unroll
        for (int nj = 0; nj < 2; ++nj)
#pragma unroll
            for (int ks = 0; ks < 2; ++ks)
                acc[1][mi][0][nj] = __builtin_amdgcn_mfma_f32_16x16x32_f16(
                    a[mi][ks], b[0][nj][ks], acc[1][mi][0][nj], 0, 0, 0);
    __builtin_amdgcn_s_setprio(0);
    __builtin_amdgcn_s_barrier();

    // ---- P4: quadrant (1,1) ----
    if (IB0) stage_half(Bg, (kt + 2) * 64, Bc, tid);
    __builtin_amdgcn_s_barrier();
    __builtin_amdgcn_s_setprio(1);
#pragma unroll
    for (int mi = 0; mi < 4; ++mi)
#pragma unroll
        for (int nj = 0; nj < 2; ++nj)
#pragma unroll
            for (int ks = 0; ks < 2; ++ks)
                acc[1][mi][1][nj] = __builtin_amdgcn_mfma_f32_16x16x32_f16(
                    a[mi][ks], b[1][nj][ks], acc[1][mi][1][nj], 0, 0, 0);
    __builtin_amdgcn_s_setprio(0);
    vwait<D1>();
    __builtin_amdgcn_s_barrier();
}

// C[m,n] = sum_k A[m,k]*Bm[n,k]; A:[M,KK] f16 rm, Bm:[N,KK] f16 rm, C f16 [M,N]
// grid 1D = Mtiles * (N/256), block 512 (8 waves: 2M x 4N), wave tile 128x64.
__global__ __launch_bounds__(512, 2) void gemm_bt_f16_256(
    const _Float16* __restrict__ A,
    const _Float16* __restrict__ Bm,
    _Float16* __restrict__ C,
    int Mtiles, int N)
{
    __shared__ _Float16 sm[65536];   // 128 KiB: [buf0 A][buf0 B][buf1 A][buf1 B]
    const int tid  = threadIdx.x;
    const int lane = tid & 63;
    const int wave = tid >> 6;
    const int wm = wave >> 2;        // 0..1
    const int wn = wave & 3;         // 0..3

    // XCD-aware swizzle; nwg = Mtiles*64 is always a multiple of 8 -> bijective
    const int nwg = (int)gridDim.x;
    const int bid = (int)blockIdx.x;
    const int swz = (bid & 7) * (nwg >> 3) + (bid >> 3);
    const int bm = swz % Mtiles;     // M-fastest: contiguous XCD chunk shares B panels
    const int bn = swz / Mtiles;

    const _Float16* Ag = A  + (long)bm * 256 * KK;
    const _Float16* Bg = Bm + (long)bn * 256 * KK;

    // fragment LDS offsets (halves). A frag (mh,mi,ks): row R = mh*128 + wm*64 +
    // mi*16 + (lane&15), chunk c = ks*4 + (lane>>4), slot = (c + (R&7)) & 7.
    // mh*128 preserves R&7 -> mh=1 is a constant +8192 fold.
    const int r15 = lane & 15;
    const int kq  = lane >> 4;
    int aoff[4][2], boff[2][2];
#pragma unroll
    for (int mi = 0; mi < 4; ++mi)
#pragma unroll
        for (int ks = 0; ks < 2; ++ks) {
            int R = wm * 64 + mi * 16 + r15;
            int c = ks * 4 + kq;
            aoff[mi][ks] = R * 64 + (((c + (R & 7)) & 7) * 8);
        }
#pragma unroll
    for (int nj = 0; nj < 2; ++nj)
#pragma unroll
        for (int ks = 0; ks < 2; ++ks) {
            int R = wn * 32 + nj * 16 + r15;
            int c = ks * 4 + kq;
            boff[nj][ks] = R * 64 + (((c + (R & 7)) & 7) * 8);
        }

    _Float16* A0b = sm;
    _Float16* B0b = sm + 16384;
    _Float16* A1b = sm + 32768;
    _Float16* B1b = sm + 49152;

    f32x4 acc[2][4][2][2] = {};

    // prologue: issue A0(0),B0(0),A1(0),B1(0),A0(1),B0(1); drain to 8 ->
    // A0(0),B0(0) complete; in flight = {A1(0),B1(0),A0(1),B0(1)} = steady state.
    stage_half(Ag,           0,  A0b,        tid);
    stage_half(Bg,           0,  B0b,        tid);
    stage_half(Ag + 128L*KK, 0,  A0b + 8192, tid);
    stage_half(Bg + 128L*KK, 0,  B0b + 8192, tid);
    stage_half(Ag,           64, A1b,        tid);
    stage_half(Bg,           64, B1b,        tid);
    vwait<8>();
    __builtin_amdgcn_s_barrier();

    for (int t = 0; t < NT - 2; t += 2) {
        tile_body<true,true,true,true,6,8>(A0b,B0b, A1b,B1b, Ag,Bg, t,   aoff,boff,tid,acc);
        tile_body<true,true,true,true,6,8>(A1b,B1b, A0b,B0b, Ag,Bg, t+1, aoff,boff,tid,acc);
    }
    // peeled tails (NT=16): tile 14 drains vmcnt(6)/vmcnt(4); tile 15 vmcnt(0).
    tile_body<true,true,false,false,6,4>(A0b,B0b, A1b,B1b, Ag,Bg, NT-2, aoff,boff,tid,acc);
    tile_body<false,false,false,false,0,-1>(A1b,B1b, A0b,B0b, Ag,Bg, NT-1, aoff,boff,tid,acc);

    // C/D 16x16 layout: col = lane&15, row = (lane>>4)*4 + reg
    const long rb0 = (long)bm * 256 + wm * 64 + (lane >> 4) * 4;
    const long cb0 = (long)bn * 256 + wn * 32 + (lane & 15);
#pragma unroll
    for (int mh = 0; mh < 2; ++mh)
#pragma unroll
    for (int mi = 0; mi < 4; ++mi)
#pragma unroll
    for (int nh = 0; nh < 2; ++nh)
#pragma unroll
    for (int nj = 0; nj < 2; ++nj) {
        const long r0 = rb0 + mh * 128 + mi * 16;
        const long c0 = cb0 + nh * 128 + nj * 16;
#pragma unroll
        for (int reg = 0; reg < 4; ++reg)
            C[(r0 + reg) * (long)N + c0] = (_Float16)acc[mh][mi][nh][nj][reg];
    }
}

// One workgroup (256 thr) per row; S is f16 [Rc, N], N=16384.
__global__ __launch_bounds__(256) void softmax_gather(
    const _Float16* __restrict__ S,
    const float* __restrict__ V,     // [N, D] fp32 text features
    const float* __restrict__ X,     // [Rc, D] (chunk-offset)
    float* __restrict__ Out,         // [Rc, D] (chunk-offset)
    const float* __restrict__ beta_p,
    const float* __restrict__ alpha_p,
    int N, int D)
{
    const int row  = blockIdx.x;
    const int tid  = threadIdx.x;
    const int lane = tid & 63;
    const int wave = tid >> 6;
    const float beta  = beta_p[0];
    const float alpha = alpha_p[0];

    __shared__ float redm[4];
    __shared__ float redl[4];
    __shared__ int   cnt;
    __shared__ int   sel_idx[MAXSEL];
    __shared__ float sel_w[MAXSEL];

    const f16x8* s8 = (const f16x8*)(S + (size_t)row * N);

    // 8 chunks of 8 halves per thread = 64 logits, held as f32x4 v[16]
    f32x4 v[16];
    float m = -3.4e38f;
#pragma unroll
    for (int j = 0; j < 8; ++j) {
        f16x8 h = s8[tid + j * 256];
        f32x4 lo, hiv;
#pragma unroll
        for (int c = 0; c < 4; ++c) { lo[c] = (float)h[c] * beta; hiv[c] = (float)h[c + 4] * beta; }
        v[2 * j] = lo; v[2 * j + 1] = hiv;
        m = fmaxf(m, fmaxf(fmaxf(lo[0], lo[1]), fmaxf(lo[2], lo[3])));
        m = fmaxf(m, fmaxf(fmaxf(hiv[0], hiv[1]), fmaxf(hiv[2], hiv[3])));
    }
#pragma unroll
    for (int off = 32; off; off >>= 1) m = fmaxf(m, __shfl_xor(m, off));
    if (lane == 0) redm[wave] = m;
    if (tid == 0) cnt = 0;
    __syncthreads();
    m = fmaxf(fmaxf(redm[0], redm[1]), fmaxf(redm[2], redm[3]));

    float l = 0.f;
#pragma unroll
    for (int j = 0; j < 16; ++j) {
        f32x4 e;
#pragma unroll
        for (int c = 0; c < 4; ++c) e[c] = exp2f((v[j][c] - m) * LOG2E);
        l += e[0] + e[1] + e[2] + e[3];
        v[j] = e;
    }
#pragma unroll
    for (int off = 32; off; off >>= 1) l += __shfl_xor(l, off);
    if (lane == 0) redl[wave] = l;
    __syncthreads();
    l = redl[0] + redl[1] + redl[2] + redl[3];

    // select entries with weight >= e^-15 (exact l; truncated numerator mass
    // <= 16384*3e-7 ~ 5e-3 -> output error << threshold)
#pragma unroll
    for (int j = 0; j < 16; ++j) {
#pragma unroll
        for (int c = 0; c < 4; ++c) {
            float e = v[j][c];
            if (e >= 3.0e-7f) {
                int p = atomicAdd(&cnt, 1);
                if (p < MAXSEL) {
                    sel_idx[p] = (tid + (j >> 1) * 256) * 8 + (j & 1) * 4 + c;
                    sel_w[p]   = e;
                }
            }
        }
    }
    __syncthreads();
    int nsel = cnt; if (nsel > MAXSEL) nsel = MAXSEL;

    const float wscale = alpha / l;
    f32x4 acc = {0.f, 0.f, 0.f, 0.f};
    for (int i = 0; i < nsel; ++i) {
        const float w = sel_w[i] * wscale;
        const f32x4 t = *(const f32x4*)(V + (size_t)sel_idx[i] * D + tid * 4);
        acc += w * t;
    }
    const f32x4 xr = ((const f32x4*)(X + (size_t)row * D))[tid];
    ((f32x4*)(Out + (size_t)row * D))[tid] = xr + acc;
}

extern "C" void kernel_launch(void* const* d_in, const int* in_sizes, int n_in,
                              void* d_out, int out_size, void* d_ws, size_t ws_size,
                              hipStream_t stream) {
    const float* x     = (const float*)d_in[0];
    const float* kimg  = (const float*)d_in[1];
    const float* vtxt  = (const float*)d_in[2];
    const float* beta  = (const float*)d_in[3];
    const float* alpha = (const float*)d_in[4];
    float* out = (float*)d_out;

    const int D = 1024;
    const int B = in_sizes[0] / D;   // 4096
    const int N = in_sizes[1] / D;   // 16384

    char* ws = (char*)d_ws;
    _Float16* x16 = (_Float16*)ws;
    _Float16* k16 = (_Float16*)(ws + (size_t)B * D * 2);
    _Float16* S   = (_Float16*)(ws + (size_t)B * D * 2 + (size_t)N * D * 2);

    // chunk rows so S (f16 [R,N]) fits in remaining workspace; R multiple of 256
    const size_t fixed = (size_t)B * D * 2 + (size_t)N * D * 2;
    size_t avail = ws_size > fixed ? ws_size - fixed : 0;
    long Rl = (long)(avail / ((size_t)N * 2));
    Rl &= ~255L;
    int R = (int)(Rl > B ? B : Rl);
    if (R < 256) R = 256;

    {
        long nx4 = (long)B * D / 4;
        long nk4 = (long)N * D / 4;
        convert_f32_f16<<<(unsigned)((nk4 + 255) / 256), 256, 0, stream>>>(kimg, k16, nk4);
        convert_f32_f16<<<(unsigned)((nx4 + 255) / 256), 256, 0, stream>>>(x, x16, nx4);
    }

    for (int r0 = 0; r0 < B; r0 += R) {
        int Rc = B - r0; if (Rc > R) Rc = R;
        int Mtiles = Rc / 256;
        dim3 g1((unsigned)(Mtiles * (N / 256)));
        gemm_bt_f16_256<<<g1, 512, 0, stream>>>(x16 + (size_t)r0 * D, k16, S, Mtiles, N);
        softmax_gather<<<(unsigned)Rc, 256, 0, stream>>>(
            S, vtxt, x + (size_t)r0 * D, out + (size_t)r0 * D, beta, alpha, N, D);
    }
}